// Round 4
// baseline (16.192 us; speedup 1.0000x reference)
//
#include <hip/hip_runtime.h>
#include <hip/hip_bf16.h>

#define NPTS 20000
#define KNB 13
#define CH 32
#define PPW 4                                  // points per wave
#define WVB 4                                  // waves per block
#define PTS_PER_BLOCK (PPW * WVB)              // 16
#define NBLOCKS (NPTS / PTS_PER_BLOCK)         // 1250 exactly

typedef __attribute__((ext_vector_type(8))) short bf16x8;
typedef __attribute__((ext_vector_type(4))) float f32x4;

// f32 -> bf16, round-half-up.
static __device__ __forceinline__ short f2bf(float x) {
    union { float f; unsigned u; } v; v.f = x;
    return (short)((v.u + 0x8000u) >> 16);
}

// ---------------------------------------------------------------------------
// One wave per 4 points. Per point n:
//   D(16x128) = F @ Wcat,  F[m] = f2bf(feats[idx[n][m]]) (rows m<13),
//   Wcat = [W0 | W1 | W2 | Bmat]  (32 x 128, bf16)
// via 8x mfma_f32_16x16x32_bf16 (lane mappings verified rounds 2-3), then
//   out[n][o] = sum_m c0[m]*D[m][o] + c1[m]*D[m][32+o]
//             + c2[m]*D[m][64+o] + vs[m]*D[m][96+o]
// Masked / out-of-range rows are killed by c*=vs=0 in the epilogue — A-rows
// need no zeroing (garbage rows multiply by 0.0f exactly).
// No LDS, no __syncthreads, one dispatch.
// ---------------------------------------------------------------------------
__global__ __launch_bounds__(256) void fused_conv(
    const float* __restrict__ feats, const float* __restrict__ coords,
    const float* __restrict__ W, const float* __restrict__ bias,
    const int* __restrict__ nbr_idx, const unsigned char* __restrict__ mask_b,
    float* __restrict__ out) {

    const int l   = threadIdx.x & 63;
    const int w   = threadIdx.x >> 6;
    const int r15 = l & 15;   // A-row / B-col / D-col
    const int g   = l >> 4;   // 0..3
    const int k8  = g * 8;

    // --- mask dtype self-detect (int32 layout: bytes at %4!=0 are all 0;
    // byte layout: ~half of 192 sampled bytes nonzero, miss prob 2^-192) ---
    const int p0 = l * 4;
    const int pred = (mask_b[p0 + 1] | mask_b[p0 + 2] | mask_b[p0 + 3]) != 0;
    const bool bytes_mode = (__ballot(pred) != 0ull);

    // --- B fragments: acc quadrant q covers Wcat cols q*16 + r15.
    // q<6: block W[q>>1], col (q&1)*16+r15;  q>=6: Bmat, col (q&1)*16+r15.
    bf16x8 bF[8];
    #pragma unroll
    for (int q = 0; q < 8; ++q) {
        const float* src = (q < 6) ? (W + (q >> 1) * (CH * CH)) : bias;
        const int ocol = (q & 1) * 16 + r15;
        #pragma unroll
        for (int e = 0; e < 8; ++e)
            bF[q][e] = f2bf(src[(k8 + e) * CH + ocol]);
    }

    const int n0 = (blockIdx.x * WVB + w) * PPW;

    #pragma unroll
    for (int pp = 0; pp < PPW; ++pp) {
        const int n = n0 + pp;

        // Row r15's neighbor (lanes r15>=13 read slot 12, then invalidated).
        const int rcl = (r15 < KNB) ? r15 : (KNB - 1);
        const int p = n * KNB + rcl;
        const int j = nbr_idx[p];
        const int mv = bytes_mode ? (int)mask_b[p] : ((const int*)mask_b)[p];
        const bool valid = (mv != 0) & (r15 < KNB);
        const int ja = valid ? j : 0;
        const float vsv = valid ? 1.0f : 0.0f;
        const float c0v = coords[ja * 3 + 0] * vsv;
        const float c1v = coords[ja * 3 + 1] * vsv;
        const float c2v = coords[ja * 3 + 2] * vsv;

        // A-frag: plain bf16 cast of feats row (no scaling, no zeroing).
        const float4* fp = (const float4*)(feats + ja * CH + k8);
        const float4 fa = fp[0], fb = fp[1];
        const float f[8] = {fa.x, fa.y, fa.z, fa.w, fb.x, fb.y, fb.z, fb.w};
        bf16x8 aF;
        #pragma unroll
        for (int e = 0; e < 8; ++e) aF[e] = f2bf(f[e]);

        f32x4 acc[8];
        #pragma unroll
        for (int q = 0; q < 8; ++q) {
            f32x4 z = {0.f, 0.f, 0.f, 0.f};
            acc[q] = __builtin_amdgcn_mfma_f32_16x16x32_bf16(aF, bF[q], z, 0, 0, 0);
        }

        // Epilogue: coord-weighted row sum. Lane holds D[4g+r][q*16+r15];
        // row-m coefficients broadcast from lane m (m<16, its r15==m).
        float s0 = 0.f, s1 = 0.f;
        #pragma unroll
        for (int r = 0; r < 4; ++r) {
            const int m = g * 4 + r;
            const float w0 = __shfl(c0v, m);
            const float w1 = __shfl(c1v, m);
            const float w2 = __shfl(c2v, m);
            const float w3 = __shfl(vsv, m);
            s0 += w0 * acc[0][r] + w1 * acc[2][r] + w2 * acc[4][r] + w3 * acc[6][r];
            s1 += w0 * acc[1][r] + w1 * acc[3][r] + w2 * acc[5][r] + w3 * acc[7][r];
        }
        s0 += __shfl_xor(s0, 16); s0 += __shfl_xor(s0, 32);
        s1 += __shfl_xor(s1, 16); s1 += __shfl_xor(s1, 32);

        if (l < 32) out[n * CH + l] = (l < 16) ? s0 : s1;  // 128B contiguous
    }
}

extern "C" void kernel_launch(void* const* d_in, const int* in_sizes, int n_in,
                              void* d_out, int out_size, void* d_ws, size_t ws_size,
                              hipStream_t stream) {
    const float* feats  = (const float*)d_in[0];
    const float* coords = (const float*)d_in[1];
    const float* W      = (const float*)d_in[2];
    const float* bias   = (const float*)d_in[3];
    const int*   nidx   = (const int*)d_in[4];
    const unsigned char* nmask = (const unsigned char*)d_in[5];
    float* out = (float*)d_out;

    fused_conv<<<NBLOCKS, 256, 0, stream>>>(feats, coords, W, bias, nidx, nmask, out);
}

// Round 5
// 14.767 us; speedup vs baseline: 1.0965x; 1.0965x over previous
//
#include <hip/hip_runtime.h>
#include <hip/hip_bf16.h>

#define NPTS 20000
#define KNB 13
#define CH 32
#define PPW 4                                  // points per wave
#define WVB 4                                  // waves per block
#define PTS_PER_BLOCK (PPW * WVB)              // 16
#define NBLOCKS (NPTS / PTS_PER_BLOCK)         // 1250 exactly

typedef __attribute__((ext_vector_type(8))) short bf16x8;
typedef __attribute__((ext_vector_type(4))) unsigned u32x4;
typedef __attribute__((ext_vector_type(4))) float f32x4;

// Pack two f32 -> one u32 of 2 bf16 (RNE). Compiles to v_cvt_pk_bf16_f32
// (1 VALU op per 2 elements) — hand-written integer rounding blocks this.
static __device__ __forceinline__ unsigned pack_bf16(float lo, float hi) {
    __hip_bfloat162 h = __float22bfloat162_rn(make_float2(lo, hi));
    union { __hip_bfloat162 h2; unsigned u; } c;
    c.h2 = h;
    return c.u;
}

// ---------------------------------------------------------------------------
// R3 structure (verified, 14.2us) + packed hardware bf16 conversion.
// One wave per 4 points. For each point n, its <=13 masked neighbors are
// rows m of a 16x128 Aug tile:
//   Aug[m] = [feats[j]*c0, feats[j]*c1, feats[j]*c2, feats[j]],  j=idx[n][m]
// D = Aug @ Wa  (Wa = [W0;W1;W2;B], 128x32) via 8x mfma_f32_16x16x32_bf16,
// then out[n][:] = sum_m D[m][:]  (masked rows zeroed in A => contribute 0).
// Row-sum: 4 reg adds + shfl_xor 16/32. No LDS, no __syncthreads, 1 dispatch.
// ---------------------------------------------------------------------------
__global__ __launch_bounds__(256) void fused_conv(
    const float* __restrict__ feats, const float* __restrict__ coords,
    const float* __restrict__ W, const float* __restrict__ bias,
    const int* __restrict__ nbr_idx, const unsigned char* __restrict__ mask_b,
    float* __restrict__ out) {

    const int l   = threadIdx.x & 63;
    const int w   = threadIdx.x >> 6;
    const int r15 = l & 15;   // A-row (neighbor slot) / B-col (channel) / D-col
    const int g   = l >> 4;   // 0..3
    const int k8  = g * 8;

    // --- mask dtype self-detect (int32 layout: bytes at %4!=0 all zero;
    // byte layout: ~half of 192 sampled bytes nonzero, miss prob 2^-192) ---
    const int p0 = l * 4;
    const int pred = (mask_b[p0 + 1] | mask_b[p0 + 2] | mask_b[p0 + 3]) != 0;
    const bool bytes_mode = (__ballot(pred) != 0ull);

    // --- B fragments: Wa[(k8+e)*32 + nt*16 + r15], L2-broadcast, loaded
    // once per wave, reused for all PPW points. Packed bf16 conversion. ----
    bf16x8 bF[4][2];
    #pragma unroll
    for (int kt = 0; kt < 4; ++kt) {
        const float* src = (kt < 3) ? (W + kt * (CH * CH)) : bias;
        #pragma unroll
        for (int nt = 0; nt < 2; ++nt) {
            u32x4 pk;
            #pragma unroll
            for (int e2 = 0; e2 < 4; ++e2) {
                const float lo = src[(k8 + 2 * e2)     * CH + nt * 16 + r15];
                const float hi = src[(k8 + 2 * e2 + 1) * CH + nt * 16 + r15];
                pk[e2] = pack_bf16(lo, hi);
            }
            bF[kt][nt] = (bf16x8)pk;
        }
    }

    const int n0 = (blockIdx.x * WVB + w) * PPW;

    #pragma unroll
    for (int pp = 0; pp < PPW; ++pp) {
        const int n = n0 + pp;

        int valid = 0, j = 0;
        if (r15 < KNB) {
            const int p = n * KNB + r15;
            j = nbr_idx[p];
            const int mv = bytes_mode ? (int)mask_b[p] : ((const int*)mask_b)[p];
            valid = (mv != 0);
        }
        const int ja = valid ? j : 0;   // safe row; zeroed via vs below

        // feats[ja][k8..k8+7]: 16B-aligned float4 pair.
        const float4* fp = (const float4*)(feats + ja * CH + k8);
        const float4 fa = fp[0], fb = fp[1];
        const float f[8] = {fa.x, fa.y, fa.z, fa.w, fb.x, fb.y, fb.z, fb.w};
        const float vs = valid ? 1.0f : 0.0f;
        const float c0 = coords[ja * 3 + 0] * vs;
        const float c1 = coords[ja * 3 + 1] * vs;
        const float c2 = coords[ja * 3 + 2] * vs;

        // A-frags: 32 muls + 16 cvt_pk per point (was 96 VALU with f2bf).
        u32x4 p0v, p1v, p2v, p3v;
        #pragma unroll
        for (int e2 = 0; e2 < 4; ++e2) {
            const float flo = f[2 * e2], fhi = f[2 * e2 + 1];
            p0v[e2] = pack_bf16(flo * c0, fhi * c0);
            p1v[e2] = pack_bf16(flo * c1, fhi * c1);
            p2v[e2] = pack_bf16(flo * c2, fhi * c2);
            p3v[e2] = pack_bf16(flo * vs, fhi * vs);
        }
        const bf16x8 a0 = (bf16x8)p0v, a1 = (bf16x8)p1v;
        const bf16x8 a2 = (bf16x8)p2v, a3 = (bf16x8)p3v;

        f32x4 acc0 = {0.f, 0.f, 0.f, 0.f};
        f32x4 acc1 = {0.f, 0.f, 0.f, 0.f};
        acc0 = __builtin_amdgcn_mfma_f32_16x16x32_bf16(a0, bF[0][0], acc0, 0, 0, 0);
        acc1 = __builtin_amdgcn_mfma_f32_16x16x32_bf16(a0, bF[0][1], acc1, 0, 0, 0);
        acc0 = __builtin_amdgcn_mfma_f32_16x16x32_bf16(a1, bF[1][0], acc0, 0, 0, 0);
        acc1 = __builtin_amdgcn_mfma_f32_16x16x32_bf16(a1, bF[1][1], acc1, 0, 0, 0);
        acc0 = __builtin_amdgcn_mfma_f32_16x16x32_bf16(a2, bF[2][0], acc0, 0, 0, 0);
        acc1 = __builtin_amdgcn_mfma_f32_16x16x32_bf16(a2, bF[2][1], acc1, 0, 0, 0);
        acc0 = __builtin_amdgcn_mfma_f32_16x16x32_bf16(a3, bF[3][0], acc0, 0, 0, 0);
        acc1 = __builtin_amdgcn_mfma_f32_16x16x32_bf16(a3, bF[3][1], acc1, 0, 0, 0);

        // Row-sum over all 16 rows (invalid rows are zero).
        float s0 = acc0[0] + acc0[1] + acc0[2] + acc0[3];
        float s1 = acc1[0] + acc1[1] + acc1[2] + acc1[3];
        s0 += __shfl_xor(s0, 16); s0 += __shfl_xor(s0, 32);
        s1 += __shfl_xor(s1, 16); s1 += __shfl_xor(s1, 32);

        if (l < 32) out[n * CH + l] = (l < 16) ? s0 : s1;  // 128B contiguous
    }
}

extern "C" void kernel_launch(void* const* d_in, const int* in_sizes, int n_in,
                              void* d_out, int out_size, void* d_ws, size_t ws_size,
                              hipStream_t stream) {
    const float* feats  = (const float*)d_in[0];
    const float* coords = (const float*)d_in[1];
    const float* W      = (const float*)d_in[2];
    const float* bias   = (const float*)d_in[3];
    const int*   nidx   = (const int*)d_in[4];
    const unsigned char* nmask = (const unsigned char*)d_in[5];
    float* out = (float*)d_out;

    fused_conv<<<NBLOCKS, 256, 0, stream>>>(feats, coords, W, bias, nidx, nmask, out);
}

// Round 6
// 14.452 us; speedup vs baseline: 1.1203x; 1.0218x over previous
//
#include <hip/hip_runtime.h>
#include <hip/hip_bf16.h>

#define NPTS 20000
#define KNB 13
#define CH 32
#define PPW 4                                  // points per wave
#define WVB 4                                  // waves per block
#define PTS_PER_BLOCK (PPW * WVB)              // 16
#define NBLOCKS (NPTS / PTS_PER_BLOCK)         // 1250 exactly

typedef __attribute__((ext_vector_type(8))) short bf16x8;
typedef __attribute__((ext_vector_type(4))) float f32x4;

// f32 -> bf16, round-half-up (2 ops; |err| <= 2^-9 rel, margin is 6x).
static __device__ __forceinline__ short f2bf(float x) {
    union { float f; unsigned u; } v; v.f = x;
    return (short)((v.u + 0x8000u) >> 16);
}

// ---------------------------------------------------------------------------
// Best-measured variant (R3, 14.21us). One wave per 4 points. For each point
// n, its <=13 masked neighbors are rows m of a 16x128 Aug tile:
//   Aug[m] = [feats[j]*c0, feats[j]*c1, feats[j]*c2, feats[j]],  j=idx[n][m]
// D = Aug @ Wa  (Wa = [W0;W1;W2;B], 128x32) via 8x mfma_f32_16x16x32_bf16
// (lane mappings verified end-to-end rounds 2-5), then
// out[n][:] = sum_m D[m][:]  (masked rows zeroed in A => contribute 0).
// Row-sum: 4 reg adds + shfl_xor 16/32. No LDS, no __syncthreads, 1 dispatch.
//
// Perf note (R4/R5 post-mortems): kernel is latency-bound (~2-3us) under a
// ~11-12us single-dispatch replay floor; VALU-work reduction (R5) and
// K-restructure + shfl epilogue (R4) were neutral and -2us respectively.
// ---------------------------------------------------------------------------
__global__ __launch_bounds__(256) void fused_conv(
    const float* __restrict__ feats, const float* __restrict__ coords,
    const float* __restrict__ W, const float* __restrict__ bias,
    const int* __restrict__ nbr_idx, const unsigned char* __restrict__ mask_b,
    float* __restrict__ out) {

    const int l   = threadIdx.x & 63;
    const int w   = threadIdx.x >> 6;
    const int r15 = l & 15;   // A-row (neighbor slot) / B-col (channel) / D-col
    const int g   = l >> 4;   // 0..3
    const int k8  = g * 8;

    // --- mask dtype self-detect (int32 layout: bytes at %4!=0 all zero;
    // byte layout: ~half of 192 sampled bytes nonzero, miss prob 2^-192) ---
    const int p0 = l * 4;
    const int pred = (mask_b[p0 + 1] | mask_b[p0 + 2] | mask_b[p0 + 3]) != 0;
    const bool bytes_mode = (__ballot(pred) != 0ull);

    // --- B fragments: Wa[(k8+e)*32 + nt*16 + r15], L2-broadcast, loaded
    // once per wave and reused for all PPW points. ------------------------
    bf16x8 bF[4][2];
    #pragma unroll
    for (int kt = 0; kt < 4; ++kt) {
        const float* src = (kt < 3) ? (W + kt * (CH * CH)) : bias;
        #pragma unroll
        for (int nt = 0; nt < 2; ++nt) {
            #pragma unroll
            for (int e = 0; e < 8; ++e)
                bF[kt][nt][e] = f2bf(src[(k8 + e) * CH + nt * 16 + r15]);
        }
    }

    const int n0 = (blockIdx.x * WVB + w) * PPW;

    #pragma unroll
    for (int pp = 0; pp < PPW; ++pp) {
        const int n = n0 + pp;

        int valid = 0, j = 0;
        if (r15 < KNB) {
            const int p = n * KNB + r15;
            j = nbr_idx[p];
            const int mv = bytes_mode ? (int)mask_b[p] : ((const int*)mask_b)[p];
            valid = (mv != 0);
        }
        const int ja = valid ? j : 0;   // safe row; zeroed via vs below

        // feats[ja][k8..k8+7] : 16B-aligned, each 16-lane group covers 8
        // consecutive floats -> wave collectively reads each row once.
        const float4* fp = (const float4*)(feats + ja * CH + k8);
        const float4 fa = fp[0], fb = fp[1];
        const float f[8] = {fa.x, fa.y, fa.z, fa.w, fb.x, fb.y, fb.z, fb.w};
        const float vs = valid ? 1.0f : 0.0f;
        const float c0 = coords[ja * 3 + 0] * vs;
        const float c1 = coords[ja * 3 + 1] * vs;
        const float c2 = coords[ja * 3 + 2] * vs;

        bf16x8 a0, a1, a2, a3;
        #pragma unroll
        for (int e = 0; e < 8; ++e) {
            const float fe = f[e];
            a0[e] = f2bf(fe * c0);
            a1[e] = f2bf(fe * c1);
            a2[e] = f2bf(fe * c2);
            a3[e] = f2bf(fe * vs);
        }

        f32x4 acc0 = {0.f, 0.f, 0.f, 0.f};
        f32x4 acc1 = {0.f, 0.f, 0.f, 0.f};
        acc0 = __builtin_amdgcn_mfma_f32_16x16x32_bf16(a0, bF[0][0], acc0, 0, 0, 0);
        acc1 = __builtin_amdgcn_mfma_f32_16x16x32_bf16(a0, bF[0][1], acc1, 0, 0, 0);
        acc0 = __builtin_amdgcn_mfma_f32_16x16x32_bf16(a1, bF[1][0], acc0, 0, 0, 0);
        acc1 = __builtin_amdgcn_mfma_f32_16x16x32_bf16(a1, bF[1][1], acc1, 0, 0, 0);
        acc0 = __builtin_amdgcn_mfma_f32_16x16x32_bf16(a2, bF[2][0], acc0, 0, 0, 0);
        acc1 = __builtin_amdgcn_mfma_f32_16x16x32_bf16(a2, bF[2][1], acc1, 0, 0, 0);
        acc0 = __builtin_amdgcn_mfma_f32_16x16x32_bf16(a3, bF[3][0], acc0, 0, 0, 0);
        acc1 = __builtin_amdgcn_mfma_f32_16x16x32_bf16(a3, bF[3][1], acc1, 0, 0, 0);

        // Row-sum over all 16 rows (invalid rows are zero).
        float s0 = acc0[0] + acc0[1] + acc0[2] + acc0[3];
        float s1 = acc1[0] + acc1[1] + acc1[2] + acc1[3];
        s0 += __shfl_xor(s0, 16); s0 += __shfl_xor(s0, 32);
        s1 += __shfl_xor(s1, 16); s1 += __shfl_xor(s1, 32);

        // Lane l<16 has channel l (s0); lane 16..31 has channel l (s1).
        if (l < 32) out[n * CH + l] = (l < 16) ? s0 : s1;  // 128B contiguous
    }
}

extern "C" void kernel_launch(void* const* d_in, const int* in_sizes, int n_in,
                              void* d_out, int out_size, void* d_ws, size_t ws_size,
                              hipStream_t stream) {
    const float* feats  = (const float*)d_in[0];
    const float* coords = (const float*)d_in[1];
    const float* W      = (const float*)d_in[2];
    const float* bias   = (const float*)d_in[3];
    const int*   nidx   = (const int*)d_in[4];
    const unsigned char* nmask = (const unsigned char*)d_in[5];
    float* out = (float*)d_out;

    fused_conv<<<NBLOCKS, 256, 0, stream>>>(feats, coords, W, bias, nidx, nmask, out);
}